// Round 5
// baseline (240.597 us; speedup 1.0000x reference)
//
#include <hip/hip_runtime.h>
#include <math.h>

// LIF recurrence: v = v + (x_t - v)/tau; s = sigmoid(v - th); v *= (1 - s)
// x: [B=32, T=512, D=2048] fp32 -> spikes s, same shape.
//
// R5: maximize (waves/SIMD) x (bytes/load-instr). Empirical law from
// R2/R4b counters: BW ~ waves x load-width, with outstanding loads per
// wave pinned at ~8 by the compiler regardless of source-level rings
// (R4b: VGPR=36 proved the scheduler sinks prefetch loads to consumers).
//   R2 : 8 waves/SIMD x 256B = 2.5 TB/s
//   R4b: 2 waves/SIMD x 1KB  = 2.8 TB/s
// -> back-solved loaded latency ~5-6k cyc; purely in-flight-bytes limited.
// This round: BOTH factors maxed. S=32 segments (SEG=16, W=16) x f32x4:
// 524288 threads = 8192 waves = 8 waves/SIMD at 1KB/load-instr (4x the
// in-flight product of any previous round). No prefetch machinery — TLP
// does the hiding; per-chunk load->wait->compute is fine since
// compute(~300cy) << latency(~5k cy).
// Warmup W=16 correctness: per-step Jacobian = 0.5*|(1-s)-v*s*(1-s)| <= 0.5
// (worst case v->-inf), so cold-start error <= 0.5^16*|v|max ~ 8e-5 in v
// -> ~2e-5 in s, invisible under the measured 0.0039 absmax floor.
// Work is 2x ideal but VALU was at 16% — compute is free. Reads are 2x but
// L3 absorbs re-reads (R4b FETCH=98MB < 134MB input).
// __launch_bounds__(256,8) caps VGPR at 64: buf 8xf32x4=32 + state fits.
// Plain (cached) loads for x — warm re-reads want L2/L3 residency;
// nontemporal stores — output is never re-read.

#define TAU_INV 0.5f
#define TH 1.0f

typedef __attribute__((ext_vector_type(4))) float f32x4;

constexpr int BATCH = 32;
constexpr int TT = 512;
constexpr int DD = 2048;
constexpr int S = 32;           // segments per chain
constexpr int SEG = TT / S;     // 16 stored steps per thread
constexpr int W = 16;           // warmup steps
constexpr int U = 8;            // steps per chunk
constexpr int NC_W = W / U;     // 2 warmup chunks
constexpr int NC_M = SEG / U;   // 2 stored chunks
constexpr int NC = NC_W + NC_M; // 4 chunks

__global__ __launch_bounds__(256, 8) void lif_kernel(const float* __restrict__ x,
                                                     float* __restrict__ out) {
    int tid = blockIdx.x * blockDim.x + threadIdx.x;  // [0, B*S*D/4)
    int d4 = tid & 511;          // group of 4 d-values (fast index)
    int sg = (tid >> 9) & (S - 1);  // segment — uniform per block
    int b = tid >> 14;
    int d = d4 * 4;
    const int t0 = sg * SEG;
    const bool warm = (sg != 0);

    // Warmup reads [t0-W, t0) for sg>0; sg==0 reads its own [t0, t0+W)
    // as a dummy (uniform code path) and resets v=0 after.
    const float* xw = x + ((size_t)b * TT + (warm ? t0 - W : t0)) * DD + d;
    const float* xm = x + ((size_t)b * TT + t0) * DD + d;
    float* om = out + ((size_t)b * TT + t0) * DD + d;

    float v0 = 0.0f, v1 = 0.0f, v2 = 0.0f, v3 = 0.0f;

    #pragma unroll
    for (int c = 0; c < NC; ++c) {
        // Load chunk c (8 x dwordx4 = 8KB per lane-group, 1KB/wave-instr).
        const float* base = (c < NC_W)
                                ? xw + (size_t)c * U * DD
                                : xm + (size_t)(c - NC_W) * U * DD;
        f32x4 buf[U];
        #pragma unroll
        for (int i = 0; i < U; ++i)
            buf[i] = *reinterpret_cast<const f32x4*>(base + (size_t)i * DD);

        // Compute chunk c: 8 steps x 4 independent chains (4-way ILP).
        #pragma unroll
        for (int i = 0; i < U; ++i) {
            float s0, s1, s2, s3;
            v0 = v0 + (buf[i].x - v0) * TAU_INV;
            v1 = v1 + (buf[i].y - v1) * TAU_INV;
            v2 = v2 + (buf[i].z - v2) * TAU_INV;
            v3 = v3 + (buf[i].w - v3) * TAU_INV;
            s0 = __builtin_amdgcn_rcpf(1.0f + __expf(TH - v0));
            s1 = __builtin_amdgcn_rcpf(1.0f + __expf(TH - v1));
            s2 = __builtin_amdgcn_rcpf(1.0f + __expf(TH - v2));
            s3 = __builtin_amdgcn_rcpf(1.0f + __expf(TH - v3));
            v0 = v0 * (1.0f - s0);
            v1 = v1 * (1.0f - s1);
            v2 = v2 * (1.0f - s2);
            v3 = v3 * (1.0f - s3);
            if (c >= NC_W) {
                f32x4 sv = {s0, s1, s2, s3};
                __builtin_nontemporal_store(
                    sv, reinterpret_cast<f32x4*>(
                            om + (size_t)((c - NC_W) * U + i) * DD));
            }
        }

        // sg==0's warmup was a dummy — restore true initial state.
        // Uniform per block (sg uniform), no divergence.
        if (c == NC_W - 1) {
            if (!warm) { v0 = 0.0f; v1 = 0.0f; v2 = 0.0f; v3 = 0.0f; }
        }
    }
}

extern "C" void kernel_launch(void* const* d_in, const int* in_sizes, int n_in,
                              void* d_out, int out_size, void* d_ws, size_t ws_size,
                              hipStream_t stream) {
    const float* x = (const float*)d_in[0];
    float* out = (float*)d_out;
    const int threads = 256;
    const int total = BATCH * S * (DD / 4);              // 524288 threads
    const int blocks = total / threads;                  // 2048
    lif_kernel<<<blocks, threads, 0, stream>>>(x, out);
}